// Round 2
// baseline (1197.492 us; speedup 1.0000x reference)
//
#include <hip/hip_runtime.h>

// Problem constants
#define BB 64
#define LL 256
#define DV 512
#define DT 41
#define NT 32
#define MM 32
#define VV 64
#define KK 8
#define D2 1106          // 2*(DV+DT)
#define KP 1120          // K padded to 35*32
#define FIVE_DV 2560

// Output flat offsets (floats)
#define OFF_NEWH 0ULL
#define OFF_C    9060352ULL
#define OFF_NEWD 17448960ULL
#define OFF_LOSS 51003392ULL
#define OFF_DT   51003393ULL

typedef __bf16 bf16x8 __attribute__((ext_vector_type(8)));
typedef float f32x4 __attribute__((ext_vector_type(4)));
typedef unsigned short u16x8 __attribute__((ext_vector_type(8)));

__device__ __forceinline__ unsigned short f2bf(float f) {
    unsigned u = __float_as_uint(f);
    u = (u + 0x7fffu + ((u >> 16) & 1u)) >> 16;
    return (unsigned short)u;
}
__device__ __forceinline__ float bf2f(unsigned short h) {
    return __uint_as_float(((unsigned)h) << 16);
}
__device__ __forceinline__ float sigm(float x) {
    return 1.0f / (1.0f + __expf(-x));
}
__device__ __forceinline__ float tanh_f(float x) {
    return 1.0f - 2.0f / (__expf(2.0f * x) + 1.0f);
}

// async global->LDS, 16B per lane; lds must be wave-uniform, data lands at
// lds + lane*16
__device__ __forceinline__ void gll16(void* lds, const void* g) {
    __builtin_amdgcn_global_load_lds(
        (const __attribute__((address_space(1))) unsigned int*)g,
        (__attribute__((address_space(3))) unsigned int*)lds, 16, 0, 0);
}

// ---------------------------------------------------------------------------
// build padded bf16 hlr = concat(hl, hr) with zero K-pad. grid 16384 x 256
__global__ __launch_bounds__(256) void k_hlr(const float* __restrict__ hl,
                                             const float* __restrict__ hr,
                                             unsigned short* __restrict__ hlr) {
    int row = blockIdx.x;
    int t = threadIdx.x;
    size_t sbase = (size_t)row * 553;
    size_t obase = (size_t)row * KP;
    for (int q = 0; q < 5; ++q) {
        int k = t + q * 256;
        if (k < KP) {
            float v = 0.0f;
            if (k < 553) v = hl[sbase + k];
            else if (k < D2) v = hr[sbase + (k - 553)];
            hlr[obase + k] = f2bf(v);
        }
    }
}

// ---------------------------------------------------------------------------
// comp_W fp32 [e][k][n] -> bf16 transposed [e][n][KP] (k-pad zeros)
// grid (80, 35, 32) x 256 (LDS 32x33 tile transpose)
__global__ __launch_bounds__(256) void k_wconv(const float* __restrict__ W,
                                               unsigned short* __restrict__ Wt) {
    __shared__ float tile[32][33];
    int e = blockIdx.z;
    int k0 = blockIdx.y * 32;
    int n0 = blockIdx.x * 32;
    int t = threadIdx.x;
    int c = t & 31;          // n-local
    int r0 = (t >> 5) * 4;   // k-local base
#pragma unroll
    for (int rr = 0; rr < 4; ++rr) {
        int r = r0 + rr;
        int k = k0 + r;
        float v = 0.0f;
        if (k < D2) v = W[((size_t)e * D2 + k) * FIVE_DV + n0 + c];
        tile[c][r] = v;   // store transposed [n][k]
    }
    __syncthreads();
    int rn = t >> 3;            // n-local
    int ck0 = (t & 7) * 4;      // k-local chunk of 4
    ushort4 o;
    o.x = f2bf(tile[rn][ck0]);
    o.y = f2bf(tile[rn][ck0 + 1]);
    o.z = f2bf(tile[rn][ck0 + 2]);
    o.w = f2bf(tile[rn][ck0 + 3]);
    *(ushort4*)&Wt[((size_t)e * FIVE_DV + n0 + rn) * KP + k0 + ck0] = o;
}

// ---------------------------------------------------------------------------
// per-batch decoder template logits (exact fp32) + argmax codes. grid 64 x 64
__global__ __launch_bounds__(64) void k_dec(const float* __restrict__ type_emb,
                                            const float* __restrict__ dec_W,
                                            const float* __restrict__ dec_b,
                                            const int* __restrict__ tts,
                                            int* __restrict__ codes,
                                            float* __restrict__ dtf) {
    int b = blockIdx.x;
    int t = threadIdx.x;
    int tt = tts[b];
    int e = tt - 9;
    __shared__ float dv[24];
    if (t < 24) {
        float v;
        if (tt == 25) {
            int k = t / 3, c = t % 3;
            int code = (k == 0) ? 0 : 2;
            v = (c == code) ? 1.0f : 0.0f;
        } else {
            float s = dec_b[e * 24 + t];
            const float* em = type_emb + (size_t)tt * DV;
            const float* w = dec_W + (size_t)e * DV * 24 + t;
            for (int d = 0; d < DV; ++d) s += em[d] * w[(size_t)d * 24];
            v = s;
        }
        dv[t] = v;
        dtf[b * 24 + t] = v;
    }
    __syncthreads();
    if (t < 8) {
        float b0 = dv[t * 3], b1 = dv[t * 3 + 1], b2 = dv[t * 3 + 2];
        int code = 0;
        float best = b0;
        if (b1 > best) { best = b1; code = 1; }
        if (b2 > best) { best = b2; code = 2; }
        codes[b * 8 + t] = code;
    }
}

// ---------------------------------------------------------------------------
// grouped GEMM v = hlr @ W[t] + b[t], both operands bf16, async LDS staging.
// tile 128(L) x 128(N) x 32(K), 256 threads (2x2 waves of 64x64)
// grid (20, 2, 64)
__global__ __launch_bounds__(256, 2) void k_gemm2(const unsigned short* __restrict__ hlr,
                                                  const unsigned short* __restrict__ Wt,
                                                  const float* __restrict__ bias,
                                                  const int* __restrict__ tts,
                                                  unsigned short* __restrict__ vws) {
    __shared__ __align__(16) unsigned short As[128 * 32];
    __shared__ __align__(16) unsigned short Bs[128 * 32];

    int b = blockIdx.z;
    int l0 = blockIdx.y * 128;
    int n0 = blockIdx.x * 128;
    int e = tts[b] - 9;

    int tid = threadIdx.x;
    int lane = tid & 63;
    int w = tid >> 6;
    int wr = w >> 1, wc = w & 1;
    int q = lane >> 4;
    int mr = lane & 15;

    const unsigned short* Abase = hlr + (size_t)(b * LL + l0) * KP;
    const unsigned short* Bbase = Wt + ((size_t)e * FIVE_DV + n0) * KP;

    // precompute staging source offsets (swizzled k-chunk in the SOURCE so the
    // lane-contiguous LDS destination ends up XOR-swizzled)
    size_t soff[2];
#pragma unroll
    for (int i = 0; i < 2; ++i) {
        int chunk = w * 128 + i * 64 + lane;
        int row = chunk >> 2;
        int kc = (chunk & 3) ^ (row & 3);
        soff[i] = (size_t)row * KP + kc * 8;
    }
    int swz = (q ^ (mr & 3)) << 3;

    f32x4 acc[4][4];
#pragma unroll
    for (int i = 0; i < 4; ++i)
#pragma unroll
        for (int j = 0; j < 4; ++j) acc[i][j] = (f32x4)0.0f;

    for (int ks = 0; ks < 35; ++ks) {
        int k0 = ks * 32;
        __syncthreads();
#pragma unroll
        for (int i = 0; i < 2; ++i) {
            int lbase = (w * 128 + i * 64) * 8;
            gll16(&As[lbase], Abase + soff[i] + k0);
            gll16(&Bs[lbase], Bbase + soff[i] + k0);
        }
        __syncthreads();
        bf16x8 af[4], bfr[4];
#pragma unroll
        for (int mt = 0; mt < 4; ++mt)
            af[mt] = *(const bf16x8*)&As[(wr * 64 + mt * 16 + mr) * 32 + swz];
#pragma unroll
        for (int nt = 0; nt < 4; ++nt)
            bfr[nt] = *(const bf16x8*)&Bs[(wc * 64 + nt * 16 + mr) * 32 + swz];
#pragma unroll
        for (int mt = 0; mt < 4; ++mt)
#pragma unroll
            for (int nt = 0; nt < 4; ++nt)
                acc[mt][nt] = __builtin_amdgcn_mfma_f32_16x16x32_bf16(
                    af[mt], bfr[nt], acc[mt][nt], 0, 0, 0);
    }

#pragma unroll
    for (int nt = 0; nt < 4; ++nt) {
        int col = n0 + wc * 64 + nt * 16 + mr;
        float bv = bias[(size_t)e * FIVE_DV + col];
#pragma unroll
        for (int mt = 0; mt < 4; ++mt) {
            int rowg = l0 + wr * 64 + mt * 16 + q * 4;
            size_t base = ((size_t)(b * LL) + rowg) * FIVE_DV + col;
#pragma unroll
            for (int r = 0; r < 4; ++r)
                vws[base + (size_t)r * FIVE_DV] = f2bf(acc[mt][nt][r] + bv);
        }
    }
}

// ---------------------------------------------------------------------------
// FALLBACK grouped GEMM (round-1 style, reads fp32 W directly) — used only
// if ws_size can't hold the transposed bf16 weights.
__global__ __launch_bounds__(256, 2) void k_gemm(const unsigned short* __restrict__ hlr,
                                                 const float* __restrict__ W,
                                                 const float* __restrict__ bias,
                                                 const int* __restrict__ tts,
                                                 unsigned short* __restrict__ vws) {
    __shared__ __align__(16) unsigned short As[128 * 32];
    __shared__ __align__(16) unsigned short Bs[128 * 32];

    int b = blockIdx.z;
    int l0 = blockIdx.y * 128;
    int n0 = blockIdx.x * 128;
    int e = tts[b] - 9;
    const float* Wb = W + (size_t)e * D2 * FIVE_DV;

    int tid = threadIdx.x;
    int lane = tid & 63;
    int w = tid >> 6;
    int wr = w >> 1, wc = w & 1;
    int q = lane >> 4;
    int mr = lane & 15;

    int nB = tid & 127;
    int kg2 = tid >> 7;

    const unsigned short* Arow = hlr + (size_t)(b * LL + l0) * KP;

    f32x4 acc[4][4];
#pragma unroll
    for (int i = 0; i < 4; ++i)
#pragma unroll
        for (int j = 0; j < 4; ++j) acc[i][j] = (f32x4)0.0f;

    for (int ks = 0; ks < 35; ++ks) {
        int k0 = ks * 32;
        __syncthreads();
#pragma unroll
        for (int i = 0; i < 2; ++i) {
            int idx = i * 256 + tid;
            int row = idx >> 2;
            int ko = (idx & 3) * 8;
            u16x8 av = *(const u16x8*)(Arow + (size_t)row * KP + k0 + ko);
            *(u16x8*)&As[idx * 8] = av;
        }
#pragma unroll
        for (int it = 0; it < 2; ++it) {
            int kg = kg2 * 2 + it;
            int kb = kg * 8;
            u16x8 bv;
#pragma unroll
            for (int j = 0; j < 8; ++j) {
                int kk = k0 + kb + j;
                float f = (kk < D2) ? Wb[(size_t)kk * FIVE_DV + n0 + nB] : 0.0f;
                bv[j] = f2bf(f);
            }
            *(u16x8*)&Bs[nB * 32 + ((kg ^ (nB & 3)) << 3)] = bv;
        }
        __syncthreads();
        bf16x8 af[4], bfr[4];
#pragma unroll
        for (int mt = 0; mt < 4; ++mt)
            af[mt] = *(const bf16x8*)&As[(wr * 64 + mt * 16 + mr) * 32 + q * 8];
#pragma unroll
        for (int nt = 0; nt < 4; ++nt) {
            int nn = wc * 64 + nt * 16 + mr;
            bfr[nt] = *(const bf16x8*)&Bs[nn * 32 + ((q ^ (nn & 3)) << 3)];
        }
#pragma unroll
        for (int mt = 0; mt < 4; ++mt)
#pragma unroll
            for (int nt = 0; nt < 4; ++nt)
                acc[mt][nt] = __builtin_amdgcn_mfma_f32_16x16x32_bf16(
                    af[mt], bfr[nt], acc[mt][nt], 0, 0, 0);
    }

#pragma unroll
    for (int nt = 0; nt < 4; ++nt) {
        int col = n0 + wc * 64 + nt * 16 + mr;
        float bv = bias[(size_t)e * FIVE_DV + col];
#pragma unroll
        for (int mt = 0; mt < 4; ++mt) {
            int rowg = l0 + wr * 64 + mt * 16 + q * 4;
            size_t base = ((size_t)(b * LL) + rowg) * FIVE_DV + col;
#pragma unroll
            for (int r = 0; r < 4; ++r)
                vws[base + (size_t)r * FIVE_DV] = f2bf(acc[mt][nt][r] + bv);
        }
    }
}

// ---------------------------------------------------------------------------
// LSTM gating + type-predictor MLP + gumbel softmax. grid 16384 x 256
__global__ __launch_bounds__(256) void k_cell(const unsigned short* __restrict__ vws,
                                              const float* __restrict__ cl,
                                              const float* __restrict__ cr,
                                              const float* __restrict__ W1,
                                              const float* __restrict__ b1,
                                              const float* __restrict__ W2,
                                              const float* __restrict__ b2,
                                              const float* __restrict__ W3,
                                              const float* __restrict__ b3,
                                              const float* __restrict__ gumbel,
                                              float* __restrict__ out) {
    int row = blockIdx.x;
    int t = threadIdx.x;
    __shared__ float hv[512];
    __shared__ float red[256];
    __shared__ float h1[32], h2[32], zz[41];

    const unsigned short* v = vws + (size_t)row * FIVE_DV;
    size_t c_off = OFF_C + (size_t)row * DV;
    size_t h_off = (size_t)row * 553;
    size_t cc = (size_t)row * DV;

    {
        int j = 2 * t;
        unsigned int pig = *(const unsigned int*)&v[j];
        unsigned int pfl = *(const unsigned int*)&v[512 + j];
        unsigned int pfr = *(const unsigned int*)&v[1024 + j];
        unsigned int puu = *(const unsigned int*)&v[1536 + j];
        unsigned int poo = *(const unsigned int*)&v[2048 + j];
        float2 clv = *(const float2*)&cl[cc + j];
        float2 crv = *(const float2*)&cr[cc + j];
#pragma unroll
        for (int i = 0; i < 2; ++i) {
            float ig = bf2f((unsigned short)(i ? (pig >> 16) : (pig & 0xffff)));
            float fl = bf2f((unsigned short)(i ? (pfl >> 16) : (pfl & 0xffff)));
            float fr = bf2f((unsigned short)(i ? (pfr >> 16) : (pfr & 0xffff)));
            float uu = bf2f((unsigned short)(i ? (puu >> 16) : (puu & 0xffff)));
            float oo = bf2f((unsigned short)(i ? (poo >> 16) : (poo & 0xffff)));
            float cli = i ? clv.y : clv.x;
            float cri = i ? crv.y : crv.x;
            float cv = cli * sigm(fl + 1.0f) + cri * sigm(fr + 1.0f)
                     + tanh_f(uu) * sigm(ig);
            float h = sigm(oo) * tanh_f(cv);
            out[c_off + j + i] = cv;
            out[h_off + j + i] = h;
            hv[j + i] = h;
        }
    }
    __syncthreads();
    {
        int jj = t & 31, g = t >> 5;
        float p = 0.0f;
        int d0 = g * 64;
        for (int d = d0; d < d0 + 64; ++d) p += hv[d] * W1[d * 32 + jj];
        red[t] = p;
    }
    __syncthreads();
    if (t < 32) {
        float s = b1[t];
#pragma unroll
        for (int g = 0; g < 8; ++g) s += red[g * 32 + t];
        h1[t] = s > 0.0f ? s : 0.0f;
    }
    __syncthreads();
    if (t < 32) {
        float s = b2[t];
        for (int d = 0; d < 32; ++d) s += h1[d] * W2[d * 32 + t];
        h2[t] = s > 0.0f ? s : 0.0f;
    }
    __syncthreads();
    if (t < 41) {
        float s = b3[t];
        for (int d = 0; d < 32; ++d) s += h2[d] * W3[d * 41 + t];
        zz[t] = s + gumbel[(size_t)row * DT + t];
    }
    __syncthreads();
    if (t < 64) {
        float val = (t < 41) ? zz[t] : -3.4e38f;
        float m = val;
        for (int off = 32; off; off >>= 1) m = fmaxf(m, __shfl_xor(m, off, 64));
        float ex = (t < 41) ? __expf(val - m) : 0.0f;
        float s = ex;
        for (int off = 32; off; off >>= 1) s += __shfl_xor(s, off, 64);
        if (t < 41) out[h_off + 512 + t] = ex / s;
    }
}

// ---------------------------------------------------------------------------
// abstraction loss (1 block, 1 wave)
__global__ __launch_bounds__(64) void k_loss(const float* __restrict__ out,
                                             const int* __restrict__ positions,
                                             const int* __restrict__ tts,
                                             float* __restrict__ loss_out) {
    int b = threadIdx.x;
    int pos = positions[b];
    int tt = tts[b];
    size_t base = ((size_t)(b * LL + pos)) * 553 + 512;
    float mx = -3.4e38f;
    float lp_t = 0.0f;
    float lps[41];
    for (int i = 0; i < 41; ++i) {
        float p = out[base + i];
        p = fminf(fmaxf(p, 1e-10f), 1.0f);
        float lp = __logf(p);
        lps[i] = lp;
        mx = fmaxf(mx, lp);
        if (i == tt) lp_t = lp;
    }
    float s = 0.0f;
    for (int i = 0; i < 41; ++i) s += __expf(lps[i] - mx);
    float lse = mx + __logf(s);
    float val = lp_t - lse;
    float a = -val / 64.0f;
    for (int off = 32; off; off >>= 1) a += __shfl_xor(a, off, 64);
    if (b == 0) *loss_out = a;
}

// ---------------------------------------------------------------------------
// template application (new_d) + dt broadcast. grid 16384 x 256
__global__ __launch_bounds__(256) void k_newd(const float* __restrict__ dl,
                                              const float* __restrict__ dr,
                                              const int* __restrict__ codes,
                                              const float* __restrict__ dtf,
                                              float* __restrict__ newd,
                                              float* __restrict__ dtout) {
    int row = blockIdx.x;
    int t = threadIdx.x;
    int b = row >> 8;
    __shared__ int sT[32];
    __shared__ int sO[32];
    __shared__ int lens[2];
    __shared__ int cds[8];

    if (t < 2) lens[t] = 0;
    if (t < 32) sT[t] = 0;
    if (t < 8) cds[t] = codes[b * 8 + t];
    __syncthreads();
    size_t dbase = (size_t)row * (MM * VV);
    if (t < 32) {
        if (dl[dbase + (size_t)t * VV] < 0.5f) atomicAdd(&lens[0], 1);
        if (dr[dbase + (size_t)t * VV] < 0.5f) atomicAdd(&lens[1], 1);
    }
    __syncthreads();
    if (t == 0) {
        int idx = 0;
        bool done = false;
        int ll = lens[0], lr = lens[1];
        for (int k = 0; k < 8; ++k) {
            int code = cds[k];
            if (done) continue;
            if (code == 0) {
                if (ll > 0 && idx + ll <= MM) {
                    for (int m = 0; m < ll; ++m) { sT[idx + m] = 1; sO[idx + m] = m; }
                    idx += ll;
                }
            } else if (code == 1) {
                if (lr > 0 && idx + lr <= MM) {
                    for (int m = 0; m < lr; ++m) { sT[idx + m] = 2; sO[idx + m] = m; }
                    idx += lr;
                }
            } else {
                if (idx < MM) { sT[idx] = 3; done = true; }
            }
        }
    }
    __syncthreads();
#pragma unroll
    for (int rep = 0; rep < 2; ++rep) {
        int e4 = t + rep * 256;
        int m = e4 >> 4, v4 = e4 & 15;
        int st = sT[m];
        float4 val = {0.0f, 0.0f, 0.0f, 0.0f};
        if (st == 1) val = *(const float4*)(dl + dbase + (size_t)sO[m] * VV + v4 * 4);
        else if (st == 2) val = *(const float4*)(dr + dbase + (size_t)sO[m] * VV + v4 * 4);
        else if (st == 3 && v4 == 0) val.x = 1.0f;
        *(float4*)(newd + dbase + (size_t)e4 * 4) = val;
    }
    if (t < 24) dtout[(size_t)row * 24 + t] = dtf[b * 24 + t];
}

// ---------------------------------------------------------------------------
extern "C" void kernel_launch(void* const* d_in, const int* in_sizes, int n_in,
                              void* d_out, int out_size, void* d_ws, size_t ws_size,
                              hipStream_t stream) {
    const float* hl = (const float*)d_in[0];
    const float* hr = (const float*)d_in[1];
    const float* cl = (const float*)d_in[2];
    const float* cr = (const float*)d_in[3];
    const float* dl = (const float*)d_in[4];
    const float* dr = (const float*)d_in[5];
    const int* target_types = (const int*)d_in[6];
    const int* positions = (const int*)d_in[7];
    const float* comp_W = (const float*)d_in[8];
    const float* comp_b = (const float*)d_in[9];
    const float* tp_W1 = (const float*)d_in[10];
    const float* tp_b1 = (const float*)d_in[11];
    const float* tp_W2 = (const float*)d_in[12];
    const float* tp_b2 = (const float*)d_in[13];
    const float* tp_W3 = (const float*)d_in[14];
    const float* tp_b3 = (const float*)d_in[15];
    const float* dec_W = (const float*)d_in[16];
    const float* dec_b = (const float*)d_in[17];
    const float* type_emb = (const float*)d_in[18];
    const float* gumbel = (const float*)d_in[19];

    float* out = (float*)d_out;

    // ws layout: hlr bf16 | codes | dtf | Wt bf16 (transposed weights)
    const size_t HLR_BYTES = (size_t)BB * LL * KP * 2;          // 36,700,160
    const size_t WT_OFF = HLR_BYTES + 8192;                     // 16B aligned
    const size_t WT_BYTES = (size_t)NT * FIVE_DV * KP * 2;      // 183,500,800
    unsigned short* hlr = (unsigned short*)d_ws;
    int* codes = (int*)((char*)d_ws + HLR_BYTES);
    float* dtf = (float*)((char*)d_ws + HLR_BYTES + 2048);
    unsigned short* Wt = (unsigned short*)((char*)d_ws + WT_OFF);

    // v (bf16) staged inside d_out's new_d region (overwritten later by k_newd)
    unsigned short* vws = (unsigned short*)(out + OFF_NEWD);

    k_hlr<<<BB * LL, 256, 0, stream>>>(hl, hr, hlr);
    k_dec<<<BB, 64, 0, stream>>>(type_emb, dec_W, dec_b, target_types, codes, dtf);

    if (ws_size >= WT_OFF + WT_BYTES) {
        k_wconv<<<dim3(80, 35, 32), 256, 0, stream>>>(comp_W, Wt);
        k_gemm2<<<dim3(FIVE_DV / 128, LL / 128, BB), 256, 0, stream>>>(
            hlr, Wt, comp_b, target_types, vws);
    } else {
        k_gemm<<<dim3(FIVE_DV / 128, LL / 128, BB), 256, 0, stream>>>(
            hlr, comp_W, comp_b, target_types, vws);
    }

    k_cell<<<BB * LL, 256, 0, stream>>>(vws, cl, cr, tp_W1, tp_b1, tp_W2, tp_b2,
                                        tp_W3, tp_b3, gumbel, out);
    k_loss<<<1, 64, 0, stream>>>(out, positions, target_types, out + OFF_LOSS);
    k_newd<<<BB * LL, 256, 0, stream>>>(dl, dr, codes, dtf, out + OFF_NEWD,
                                        out + OFF_DT);
}

// Round 3
// 1057.322 us; speedup vs baseline: 1.1326x; 1.1326x over previous
//
#include <hip/hip_runtime.h>
#include <hip/hip_bf16.h>

// Problem constants
#define BB 64
#define LL 256
#define DV 512
#define DT 41
#define NT 32
#define MM 32
#define VV 64
#define KK 8
#define D2 1106          // 2*(DV+DT)
#define KP 1120          // K padded to 35*32
#define FIVE_DV 2560

// Output flat offsets (floats)
#define OFF_NEWH 0ULL
#define OFF_C    9060352ULL
#define OFF_NEWD 17448960ULL
#define OFF_LOSS 51003392ULL
#define OFF_DT   51003393ULL

typedef __bf16 bf16x8 __attribute__((ext_vector_type(8)));
typedef float f32x4 __attribute__((ext_vector_type(4)));
typedef unsigned short u16x8 __attribute__((ext_vector_type(8)));

__device__ __forceinline__ unsigned short f2bf(float f) {
    unsigned u = __float_as_uint(f);
    u = (u + 0x7fffu + ((u >> 16) & 1u)) >> 16;
    return (unsigned short)u;
}
__device__ __forceinline__ unsigned pack2bf(float a, float b) {
    return (unsigned)f2bf(a) | ((unsigned)f2bf(b) << 16);
}
__device__ __forceinline__ float bf2f(unsigned short h) {
    return __uint_as_float(((unsigned)h) << 16);
}
__device__ __forceinline__ float sigm(float x) {
    return 1.0f / (1.0f + __expf(-x));
}
__device__ __forceinline__ float tanh_f(float x) {
    return 1.0f - 2.0f / (__expf(2.0f * x) + 1.0f);
}

// async global->LDS, 16B per lane; data lands at lds + lane*16
__device__ __forceinline__ void gll16(void* lds, const void* g) {
    __builtin_amdgcn_global_load_lds(
        (const __attribute__((address_space(1))) unsigned int*)g,
        (__attribute__((address_space(3))) unsigned int*)lds, 16, 0, 0);
}

// ---------------------------------------------------------------------------
// build padded bf16 hlr = concat(hl, hr) with zero K-pad. grid 16384 x 256
__global__ __launch_bounds__(256) void k_hlr(const float* __restrict__ hl,
                                             const float* __restrict__ hr,
                                             unsigned short* __restrict__ hlr) {
    int row = blockIdx.x;
    int t = threadIdx.x;
    size_t sbase = (size_t)row * 553;
    size_t obase = (size_t)row * KP;
    for (int q = 0; q < 5; ++q) {
        int k = t + q * 256;
        if (k < KP) {
            float v = 0.0f;
            if (k < 553) v = hl[sbase + k];
            else if (k < D2) v = hr[sbase + (k - 553)];
            hlr[obase + k] = f2bf(v);
        }
    }
}

// ---------------------------------------------------------------------------
// per-batch decoder template logits (exact fp32) + argmax codes. grid 64 x 64
__global__ __launch_bounds__(64) void k_dec(const float* __restrict__ type_emb,
                                            const float* __restrict__ dec_W,
                                            const float* __restrict__ dec_b,
                                            const int* __restrict__ tts,
                                            int* __restrict__ codes,
                                            float* __restrict__ dtf) {
    int b = blockIdx.x;
    int t = threadIdx.x;
    int tt = tts[b];
    int e = tt - 9;
    __shared__ float dv[24];
    if (t < 24) {
        float v;
        if (tt == 25) {
            int k = t / 3, c = t % 3;
            int code = (k == 0) ? 0 : 2;
            v = (c == code) ? 1.0f : 0.0f;
        } else {
            float s = dec_b[e * 24 + t];
            const float* em = type_emb + (size_t)tt * DV;
            const float* w = dec_W + (size_t)e * DV * 24 + t;
            for (int d = 0; d < DV; ++d) s += em[d] * w[(size_t)d * 24];
            v = s;
        }
        dv[t] = v;
        dtf[b * 24 + t] = v;
    }
    __syncthreads();
    if (t < 8) {
        float b0 = dv[t * 3], b1 = dv[t * 3 + 1], b2 = dv[t * 3 + 2];
        int code = 0;
        float best = b0;
        if (b1 > best) { best = b1; code = 1; }
        if (b2 > best) { best = b2; code = 2; }
        codes[b * 8 + t] = code;
    }
}

// ---------------------------------------------------------------------------
// Fused grouped GEMM: v = hlr @ W[t] + b[t]; A bf16 via gll16, B fp32 loaded
// coalesced, converted to bf16 + transposed into LDS in-kernel.
// tile 256(L) x 128(N) x 32(K); 256 threads = 4 waves (2x2); each wave does
// two 64x64 l-halves. Grid (20 n-tiles, 64 batches). W read ONCE per block.
__global__ __launch_bounds__(256, 2) void k_gemmF(const unsigned short* __restrict__ hlr,
                                                  const float* __restrict__ W,
                                                  const float* __restrict__ bias,
                                                  const int* __restrict__ tts,
                                                  unsigned short* __restrict__ vws) {
    __shared__ __align__(16) unsigned short As[2][128 * 32];
    __shared__ __align__(16) unsigned short Bs[128 * 32];

    int b = blockIdx.y;
    int n0 = blockIdx.x * 128;
    int e = tts[b] - 9;
    const float* Wb = W + (size_t)e * D2 * FIVE_DV;

    int tid = threadIdx.x;
    int lane = tid & 63;
    int w = tid >> 6;
    int wr = w >> 1, wc = w & 1;
    int q = lane >> 4;
    int mr = lane & 15;

    const unsigned short* Abase = hlr + (size_t)(b * LL) * KP;

    // A staging: source chunk permuted so LDS physical slot row*4+(kc^(row&3))
    size_t soff[2];
#pragma unroll
    for (int i = 0; i < 2; ++i) {
        int chunk = w * 128 + i * 64 + lane;
        int row = chunk >> 2;
        int kc = (chunk & 3) ^ (row & 3);
        soff[i] = (size_t)row * KP + kc * 8;
    }
    int swzA = (q ^ (mr & 3)) << 3;

    // B staging: thread covers rows k0+4r..4r+3 at cols n0+nb..nb+3
    int r = tid >> 5;            // 0..7
    int nb = (tid & 31) * 4;     // 0..124
    int kcw = r >> 1;            // chunk of the 4 k's
    int koffw = (r & 1) * 4;     // short offset within chunk

    f32x4 acc[2][4][4];
#pragma unroll
    for (int h = 0; h < 2; ++h)
#pragma unroll
        for (int i = 0; i < 4; ++i)
#pragma unroll
            for (int j = 0; j < 4; ++j) acc[h][i][j] = (f32x4)0.0f;

    for (int ks = 0; ks < 35; ++ks) {
        int k0 = ks * 32;
        __syncthreads();
        // ---- stage A (both l-halves) via async DMA
#pragma unroll
        for (int h = 0; h < 2; ++h)
#pragma unroll
            for (int i = 0; i < 2; ++i) {
                int lbase = (w * 128 + i * 64) * 8;
                gll16(&As[h][lbase], Abase + (size_t)h * 128 * KP + soff[i] + k0);
            }
        // ---- stage B: fp32 coalesced load -> bf16 pack -> transposed LDS
        {
            float4 f[4];
#pragma unroll
            for (int i = 0; i < 4; ++i) {
                int kg = k0 + 4 * r + i;
                if (kg < D2)
                    f[i] = *(const float4*)(Wb + (size_t)kg * FIVE_DV + n0 + nb);
                else
                    f[i] = make_float4(0.f, 0.f, 0.f, 0.f);
            }
#pragma unroll
            for (int j = 0; j < 4; ++j) {
                int n = nb + j;
                int s = (n & 3) ^ ((n >> 2) & 3);
                uint2 pk;
                pk.x = pack2bf(((const float*)&f[0])[j], ((const float*)&f[1])[j]);
                pk.y = pack2bf(((const float*)&f[2])[j], ((const float*)&f[3])[j]);
                *(uint2*)&Bs[n * 32 + ((kcw ^ s) << 3) + koffw] = pk;
            }
        }
        __syncthreads();
        // ---- fragments + MFMA (B frags shared across both l-halves)
        bf16x8 bfr[4];
#pragma unroll
        for (int nt = 0; nt < 4; ++nt) {
            int n = wc * 64 + nt * 16 + mr;
            int s = (n & 3) ^ ((n >> 2) & 3);
            bfr[nt] = *(const bf16x8*)&Bs[n * 32 + ((q ^ s) << 3)];
        }
#pragma unroll
        for (int h = 0; h < 2; ++h) {
            bf16x8 af[4];
#pragma unroll
            for (int mt = 0; mt < 4; ++mt)
                af[mt] = *(const bf16x8*)&As[h][(wr * 64 + mt * 16 + mr) * 32 + swzA];
#pragma unroll
            for (int mt = 0; mt < 4; ++mt)
#pragma unroll
                for (int nt = 0; nt < 4; ++nt)
                    acc[h][mt][nt] = __builtin_amdgcn_mfma_f32_16x16x32_bf16(
                        af[mt], bfr[nt], acc[h][mt][nt], 0, 0, 0);
        }
    }

    // ---- epilogue: add bias, write bf16 v
#pragma unroll
    for (int nt = 0; nt < 4; ++nt) {
        int col = n0 + wc * 64 + nt * 16 + mr;
        float bv = bias[(size_t)e * FIVE_DV + col];
#pragma unroll
        for (int h = 0; h < 2; ++h)
#pragma unroll
            for (int mt = 0; mt < 4; ++mt) {
                int rowg = h * 128 + wr * 64 + mt * 16 + q * 4;
                size_t base = ((size_t)(b * LL) + rowg) * FIVE_DV + col;
#pragma unroll
                for (int rr = 0; rr < 4; ++rr)
                    vws[base + (size_t)rr * FIVE_DV] = f2bf(acc[h][mt][nt][rr] + bv);
            }
    }
}

// ---------------------------------------------------------------------------
// LSTM gating + type-predictor MLP + gumbel softmax. grid 16384 x 256
__global__ __launch_bounds__(256) void k_cell(const unsigned short* __restrict__ vws,
                                              const float* __restrict__ cl,
                                              const float* __restrict__ cr,
                                              const float* __restrict__ W1,
                                              const float* __restrict__ b1,
                                              const float* __restrict__ W2,
                                              const float* __restrict__ b2,
                                              const float* __restrict__ W3,
                                              const float* __restrict__ b3,
                                              const float* __restrict__ gumbel,
                                              float* __restrict__ out) {
    int row = blockIdx.x;
    int t = threadIdx.x;
    __shared__ float hv[512];
    __shared__ float red[256];
    __shared__ float h1[32], h2[32], zz[41];

    const unsigned short* v = vws + (size_t)row * FIVE_DV;
    size_t c_off = OFF_C + (size_t)row * DV;
    size_t h_off = (size_t)row * 553;
    size_t cc = (size_t)row * DV;

    {
        int j = 2 * t;
        unsigned int pig = *(const unsigned int*)&v[j];
        unsigned int pfl = *(const unsigned int*)&v[512 + j];
        unsigned int pfr = *(const unsigned int*)&v[1024 + j];
        unsigned int puu = *(const unsigned int*)&v[1536 + j];
        unsigned int poo = *(const unsigned int*)&v[2048 + j];
        float2 clv = *(const float2*)&cl[cc + j];
        float2 crv = *(const float2*)&cr[cc + j];
#pragma unroll
        for (int i = 0; i < 2; ++i) {
            float ig = bf2f((unsigned short)(i ? (pig >> 16) : (pig & 0xffff)));
            float fl = bf2f((unsigned short)(i ? (pfl >> 16) : (pfl & 0xffff)));
            float fr = bf2f((unsigned short)(i ? (pfr >> 16) : (pfr & 0xffff)));
            float uu = bf2f((unsigned short)(i ? (puu >> 16) : (puu & 0xffff)));
            float oo = bf2f((unsigned short)(i ? (poo >> 16) : (poo & 0xffff)));
            float cli = i ? clv.y : clv.x;
            float cri = i ? crv.y : crv.x;
            float cv = cli * sigm(fl + 1.0f) + cri * sigm(fr + 1.0f)
                     + tanh_f(uu) * sigm(ig);
            float h = sigm(oo) * tanh_f(cv);
            out[c_off + j + i] = cv;
            out[h_off + j + i] = h;
            hv[j + i] = h;
        }
    }
    __syncthreads();
    {
        int jj = t & 31, g = t >> 5;
        float p = 0.0f;
        int d0 = g * 64;
        for (int d = d0; d < d0 + 64; ++d) p += hv[d] * W1[d * 32 + jj];
        red[t] = p;
    }
    __syncthreads();
    if (t < 32) {
        float s = b1[t];
#pragma unroll
        for (int g = 0; g < 8; ++g) s += red[g * 32 + t];
        h1[t] = s > 0.0f ? s : 0.0f;
    }
    __syncthreads();
    if (t < 32) {
        float s = b2[t];
        for (int d = 0; d < 32; ++d) s += h1[d] * W2[d * 32 + t];
        h2[t] = s > 0.0f ? s : 0.0f;
    }
    __syncthreads();
    if (t < 41) {
        float s = b3[t];
        for (int d = 0; d < 32; ++d) s += h2[d] * W3[d * 41 + t];
        zz[t] = s + gumbel[(size_t)row * DT + t];
    }
    __syncthreads();
    if (t < 64) {
        float val = (t < 41) ? zz[t] : -3.4e38f;
        float m = val;
        for (int off = 32; off; off >>= 1) m = fmaxf(m, __shfl_xor(m, off, 64));
        float ex = (t < 41) ? __expf(val - m) : 0.0f;
        float s = ex;
        for (int off = 32; off; off >>= 1) s += __shfl_xor(s, off, 64);
        if (t < 41) out[h_off + 512 + t] = ex / s;
    }
}

// ---------------------------------------------------------------------------
// abstraction loss (1 block, 1 wave)
__global__ __launch_bounds__(64) void k_loss(const float* __restrict__ out,
                                             const int* __restrict__ positions,
                                             const int* __restrict__ tts,
                                             float* __restrict__ loss_out) {
    int b = threadIdx.x;
    int pos = positions[b];
    int tt = tts[b];
    size_t base = ((size_t)(b * LL + pos)) * 553 + 512;
    float mx = -3.4e38f;
    float lp_t = 0.0f;
    float lps[41];
    for (int i = 0; i < 41; ++i) {
        float p = out[base + i];
        p = fminf(fmaxf(p, 1e-10f), 1.0f);
        float lp = __logf(p);
        lps[i] = lp;
        mx = fmaxf(mx, lp);
        if (i == tt) lp_t = lp;
    }
    float s = 0.0f;
    for (int i = 0; i < 41; ++i) s += __expf(lps[i] - mx);
    float lse = mx + __logf(s);
    float val = lp_t - lse;
    float a = -val / 64.0f;
    for (int off = 32; off; off >>= 1) a += __shfl_xor(a, off, 64);
    if (b == 0) *loss_out = a;
}

// ---------------------------------------------------------------------------
// template application (new_d) + dt broadcast. grid 16384 x 256
__global__ __launch_bounds__(256) void k_newd(const float* __restrict__ dl,
                                              const float* __restrict__ dr,
                                              const int* __restrict__ codes,
                                              const float* __restrict__ dtf,
                                              float* __restrict__ newd,
                                              float* __restrict__ dtout) {
    int row = blockIdx.x;
    int t = threadIdx.x;
    int b = row >> 8;
    __shared__ int sT[32];
    __shared__ int sO[32];
    __shared__ int lens[2];
    __shared__ int cds[8];

    if (t < 2) lens[t] = 0;
    if (t < 32) sT[t] = 0;
    if (t < 8) cds[t] = codes[b * 8 + t];
    __syncthreads();
    size_t dbase = (size_t)row * (MM * VV);
    if (t < 32) {
        if (dl[dbase + (size_t)t * VV] < 0.5f) atomicAdd(&lens[0], 1);
        if (dr[dbase + (size_t)t * VV] < 0.5f) atomicAdd(&lens[1], 1);
    }
    __syncthreads();
    if (t == 0) {
        int idx = 0;
        bool done = false;
        int ll = lens[0], lr = lens[1];
        for (int k = 0; k < 8; ++k) {
            int code = cds[k];
            if (done) continue;
            if (code == 0) {
                if (ll > 0 && idx + ll <= MM) {
                    for (int m = 0; m < ll; ++m) { sT[idx + m] = 1; sO[idx + m] = m; }
                    idx += ll;
                }
            } else if (code == 1) {
                if (lr > 0 && idx + lr <= MM) {
                    for (int m = 0; m < lr; ++m) { sT[idx + m] = 2; sO[idx + m] = m; }
                    idx += lr;
                }
            } else {
                if (idx < MM) { sT[idx] = 3; done = true; }
            }
        }
    }
    __syncthreads();
#pragma unroll
    for (int rep = 0; rep < 2; ++rep) {
        int e4 = t + rep * 256;
        int m = e4 >> 4, v4 = e4 & 15;
        int st = sT[m];
        float4 val = {0.0f, 0.0f, 0.0f, 0.0f};
        if (st == 1) val = *(const float4*)(dl + dbase + (size_t)sO[m] * VV + v4 * 4);
        else if (st == 2) val = *(const float4*)(dr + dbase + (size_t)sO[m] * VV + v4 * 4);
        else if (st == 3 && v4 == 0) val.x = 1.0f;
        *(float4*)(newd + dbase + (size_t)e4 * 4) = val;
    }
    if (t < 24) dtout[(size_t)row * 24 + t] = dtf[b * 24 + t];
}

// ---------------------------------------------------------------------------
extern "C" void kernel_launch(void* const* d_in, const int* in_sizes, int n_in,
                              void* d_out, int out_size, void* d_ws, size_t ws_size,
                              hipStream_t stream) {
    const float* hl = (const float*)d_in[0];
    const float* hr = (const float*)d_in[1];
    const float* cl = (const float*)d_in[2];
    const float* cr = (const float*)d_in[3];
    const float* dl = (const float*)d_in[4];
    const float* dr = (const float*)d_in[5];
    const int* target_types = (const int*)d_in[6];
    const int* positions = (const int*)d_in[7];
    const float* comp_W = (const float*)d_in[8];
    const float* comp_b = (const float*)d_in[9];
    const float* tp_W1 = (const float*)d_in[10];
    const float* tp_b1 = (const float*)d_in[11];
    const float* tp_W2 = (const float*)d_in[12];
    const float* tp_b2 = (const float*)d_in[13];
    const float* tp_W3 = (const float*)d_in[14];
    const float* tp_b3 = (const float*)d_in[15];
    const float* dec_W = (const float*)d_in[16];
    const float* dec_b = (const float*)d_in[17];
    const float* type_emb = (const float*)d_in[18];
    const float* gumbel = (const float*)d_in[19];

    float* out = (float*)d_out;

    // ws layout: hlr bf16 | codes | dtf
    const size_t HLR_BYTES = (size_t)BB * LL * KP * 2;   // 36,700,160
    unsigned short* hlr = (unsigned short*)d_ws;
    int* codes = (int*)((char*)d_ws + HLR_BYTES);
    float* dtf = (float*)((char*)d_ws + HLR_BYTES + 2048);

    // v (bf16) staged inside d_out's new_d region (overwritten later by k_newd)
    unsigned short* vws = (unsigned short*)(out + OFF_NEWD);

    k_hlr<<<BB * LL, 256, 0, stream>>>(hl, hr, hlr);
    k_dec<<<BB, 64, 0, stream>>>(type_emb, dec_W, dec_b, target_types, codes, dtf);
    k_gemmF<<<dim3(FIVE_DV / 128, BB), 256, 0, stream>>>(
        hlr, comp_W, comp_b, target_types, vws);
    k_cell<<<BB * LL, 256, 0, stream>>>(vws, cl, cr, tp_W1, tp_b1, tp_W2, tp_b2,
                                        tp_W3, tp_b3, gumbel, out);
    k_loss<<<1, 64, 0, stream>>>(out, positions, target_types, out + OFF_LOSS);
    k_newd<<<BB * LL, 256, 0, stream>>>(dl, dr, codes, dtf, out + OFF_NEWD,
                                        out + OFF_DT);
}